// Round 2
// baseline (1211.039 us; speedup 1.0000x reference)
//
#include <hip/hip_runtime.h>

typedef __bf16 bf16;
typedef __bf16 bf16x8 __attribute__((ext_vector_type(8)));
typedef float f32x4 __attribute__((ext_vector_type(4)));

// Problem constants
#define BB 2
#define SS 2048
#define DIM 4096
#define KVDIM 1024
#define NH 32
#define NKV 8
#define HD 128
#define NEGINF (-1e30f)

__device__ __forceinline__ void async16(void* lds, const void* gmem) {
    __builtin_amdgcn_global_load_lds(
        (const __attribute__((address_space(1))) void*)gmem,
        (__attribute__((address_space(3))) void*)lds, 16, 0, 0);
}

__device__ __forceinline__ f32x4 mfma16(bf16x8 a, bf16x8 b, f32x4 c) {
    return __builtin_amdgcn_mfma_f32_16x16x32_bf16(a, b, c, 0, 0, 0);
}

// ---------------------------------------------------------------------------
// Per-tensor dtype detection. Read first <=8192 elements AS bf16: genuine
// bf16 data in this problem is bounded (|x|<~5, |w|<~0.2, |trig|<=1); fp32
// storage read as bf16 yields random-exponent garbage in the mantissa
// halves -> |v|>1e4 or NaN with probability ~1 over thousands of samples.
// flags[i] = 1  <=>  tensor i is fp32 storage.
// ---------------------------------------------------------------------------
struct DetectArgs { const void* p[7]; int n[7]; };

__global__ void detect_dtypes(DetectArgs a, int* flags) {
    __shared__ int bad;
    const int ti = blockIdx.x;
    if (threadIdx.x == 0) bad = 0;
    __syncthreads();
    const bf16* s = (const bf16*)a.p[ti];
    int n = a.n[ti];
    int take = n < 8192 ? n : 8192;
    int lbad = 0;
    for (int i = threadIdx.x; i < take; i += 256) {
        float f = (float)s[i];
        if (!(f > -1e4f && f < 1e4f)) lbad = 1;  // catches huge AND NaN
    }
    if (lbad) atomicOr(&bad, 1);
    __syncthreads();
    if (threadIdx.x == 0) flags[ti] = bad;
}

// Normalize a tensor into bf16 (convert if fp32, copy if already bf16).
__global__ void convert_to_bf16(const void* __restrict__ src, bf16* __restrict__ dst,
                                int n8, const int* __restrict__ flagp) {
    int i = blockIdx.x * 256 + threadIdx.x;
    if (i >= n8) return;
    if (*flagp) {
        const float* s = (const float*)src + (size_t)i * 8;
        bf16x8 v;
#pragma unroll
        for (int j = 0; j < 8; ++j) v[j] = (bf16)s[j];
        *(bf16x8*)(dst + (size_t)i * 8) = v;
    } else {
        *(bf16x8*)(dst + (size_t)i * 8) = *((const bf16x8*)src + i);
    }
}

// ---------------------------------------------------------------------------
// NT GEMM: C[M,N] = A[M,K] * B[N,K]^T  (bf16 in, bf16 out).  m97 structure:
// 128x128 tile, BK=32, 256 threads, global_load_lds width=16 staging,
// 4x4 16x16x32 MFMAs per wave.
// ---------------------------------------------------------------------------
__global__ __launch_bounds__(256, 2)
void gemm_nt(const bf16* __restrict__ A, const bf16* __restrict__ B,
             bf16* __restrict__ C, int M, int N, int K) {
    __shared__ bf16 As[128 * 32];
    __shared__ bf16 Bs[128 * 32];
    const int t = threadIdx.x;
    const int lane = t & 63;
    const int w = t >> 6;
    const int l15 = lane & 15, quad = lane >> 4;
    const int m0 = blockIdx.y * 128, n0 = blockIdx.x * 128;
    const int wm = (w >> 1) * 64, wn = (w & 1) * 64;

    f32x4 acc[4][4] = {};

    for (int k0 = 0; k0 < K; k0 += 32) {
#pragma unroll
        for (int i = 0; i < 2; ++i) {
            int s = i * 256 + t;
            int row = s >> 2, ks = s & 3;
            async16((char*)As + (size_t)s * 16,
                    A + (size_t)(m0 + row) * K + k0 + ks * 8);
            async16((char*)Bs + (size_t)s * 16,
                    B + (size_t)(n0 + row) * K + k0 + ks * 8);
        }
        __syncthreads();

        bf16x8 af[4], bfr[4];
#pragma unroll
        for (int i = 0; i < 4; ++i)
            af[i] = *(const bf16x8*)(As + (wm + i * 16 + l15) * 32 + quad * 8);
#pragma unroll
        for (int j = 0; j < 4; ++j)
            bfr[j] = *(const bf16x8*)(Bs + (wn + j * 16 + l15) * 32 + quad * 8);
#pragma unroll
        for (int i = 0; i < 4; ++i)
#pragma unroll
            for (int j = 0; j < 4; ++j)
                acc[i][j] = mfma16(af[i], bfr[j], acc[i][j]);
        __syncthreads();
    }
#pragma unroll
    for (int i = 0; i < 4; ++i)
#pragma unroll
        for (int j = 0; j < 4; ++j) {
            int col = n0 + wn + j * 16 + l15;
#pragma unroll
            for (int r = 0; r < 4; ++r) {
                int row = m0 + wm + i * 16 + quad * 4 + r;
                C[(size_t)row * N + col] = (bf16)acc[i][j][r];
            }
        }
}

// Same GEMM but output dtype selected at runtime (fp32 if *flagp else bf16).
__global__ __launch_bounds__(256, 2)
void gemm_nt_out(const bf16* __restrict__ A, const bf16* __restrict__ B,
                 void* __restrict__ C, int M, int N, int K,
                 const int* __restrict__ flagp) {
    __shared__ bf16 As[128 * 32];
    __shared__ bf16 Bs[128 * 32];
    const int t = threadIdx.x;
    const int lane = t & 63;
    const int w = t >> 6;
    const int l15 = lane & 15, quad = lane >> 4;
    const int m0 = blockIdx.y * 128, n0 = blockIdx.x * 128;
    const int wm = (w >> 1) * 64, wn = (w & 1) * 64;
    const int f32out = *flagp;

    f32x4 acc[4][4] = {};

    for (int k0 = 0; k0 < K; k0 += 32) {
#pragma unroll
        for (int i = 0; i < 2; ++i) {
            int s = i * 256 + t;
            int row = s >> 2, ks = s & 3;
            async16((char*)As + (size_t)s * 16,
                    A + (size_t)(m0 + row) * K + k0 + ks * 8);
            async16((char*)Bs + (size_t)s * 16,
                    B + (size_t)(n0 + row) * K + k0 + ks * 8);
        }
        __syncthreads();

        bf16x8 af[4], bfr[4];
#pragma unroll
        for (int i = 0; i < 4; ++i)
            af[i] = *(const bf16x8*)(As + (wm + i * 16 + l15) * 32 + quad * 8);
#pragma unroll
        for (int j = 0; j < 4; ++j)
            bfr[j] = *(const bf16x8*)(Bs + (wn + j * 16 + l15) * 32 + quad * 8);
#pragma unroll
        for (int i = 0; i < 4; ++i)
#pragma unroll
            for (int j = 0; j < 4; ++j)
                acc[i][j] = mfma16(af[i], bfr[j], acc[i][j]);
        __syncthreads();
    }
#pragma unroll
    for (int i = 0; i < 4; ++i)
#pragma unroll
        for (int j = 0; j < 4; ++j) {
            int col = n0 + wn + j * 16 + l15;
#pragma unroll
            for (int r = 0; r < 4; ++r) {
                int row = m0 + wm + i * 16 + quad * 4 + r;
                if (f32out)
                    ((float*)C)[(size_t)row * N + col] = acc[i][j][r];
                else
                    ((bf16*)C)[(size_t)row * N + col] = (bf16)acc[i][j][r];
            }
        }
}

// ---------------------------------------------------------------------------
// RoPE (in place) on Q (scaled by 1/sqrt(HD)*log2e for base-2 softmax) and K.
// ---------------------------------------------------------------------------
__device__ __forceinline__ void rope8(bf16* p, const bf16* fc, const bf16* fs,
                                      int s, int i0, float sc) {
    bf16x8 v = *(bf16x8*)p;
    bf16x8 o;
#pragma unroll
    for (int j = 0; j < 4; ++j) {
        float tr = (float)v[2 * j], ti = (float)v[2 * j + 1];
        float cc = (float)fc[s * 64 + i0 + j];
        float sn = (float)fs[s * 64 + i0 + j];
        o[2 * j]     = (bf16)((tr * cc - ti * sn) * sc);
        o[2 * j + 1] = (bf16)((tr * sn + ti * cc) * sc);
    }
    *(bf16x8*)p = o;
}

__global__ void rope_kernel(bf16* __restrict__ Q, bf16* __restrict__ Kr,
                            const bf16* __restrict__ fc, const bf16* __restrict__ fs) {
    const float qscale = 0.08838834764831845f * 1.4426950408889634f;
    int u = blockIdx.x * 256 + threadIdx.x;
    const int QU = (DIM * (BB * SS)) / 8;
    if (u < QU) {
        int row = u >> 9;
        int c = (u & 511) * 8;
        rope8(Q + (size_t)row * DIM + c, fc, fs, row & (SS - 1), (c >> 1) & 63, qscale);
    } else {
        u -= QU;
        int row = u >> 7;
        int c = (u & 127) * 8;
        rope8(Kr + (size_t)row * KVDIM + c, fc, fs, row & (SS - 1), (c >> 1) & 63, 1.0f);
    }
}

// ---------------------------------------------------------------------------
// Transpose V -> Vt[((b*NKV+kvh)*HD + d)*S + s]
// ---------------------------------------------------------------------------
__global__ void transpose_v(const bf16* __restrict__ V, bf16* __restrict__ Vt) {
    __shared__ bf16 tile[64][74];
    const int st = blockIdx.x;
    const int ct = blockIdx.y;
    const int b = blockIdx.z;
    const int s0 = st * 64;
    const int kvh = ct >> 1, d0 = (ct & 1) * 64;
    const int t = threadIdx.x;
#pragma unroll
    for (int i = 0; i < 2; ++i) {
        int o = i * 256 + t;
        int r = o >> 3, c8 = (o & 7) * 8;
        bf16x8 v = *(const bf16x8*)(V + (size_t)(b * SS + s0 + r) * KVDIM + kvh * HD + d0 + c8);
#pragma unroll
        for (int j = 0; j < 8; ++j) tile[r][c8 + j] = v[j];
    }
    __syncthreads();
#pragma unroll
    for (int i = 0; i < 2; ++i) {
        int o = i * 256 + t;
        int sseg = (o & 7) * 8, dl = o >> 3;
        bf16x8 v;
#pragma unroll
        for (int j = 0; j < 8; ++j) v[j] = tile[sseg + j][dl];
        *(bf16x8*)(Vt + ((size_t)((b * NKV + kvh) * HD) + d0 + dl) * SS + s0 + sseg) = v;
    }
}

// ---------------------------------------------------------------------------
// Flash attention (causal, GQA), base-2 online softmax, finite mask value.
// ---------------------------------------------------------------------------
__global__ __launch_bounds__(256, 2)
void flash_attn(const bf16* __restrict__ Q, const bf16* __restrict__ Kr,
                const bf16* __restrict__ Vt, bf16* __restrict__ AO) {
    __shared__ bf16 Ks[64 * 128];
    __shared__ bf16 Vts[128 * 64];
    __shared__ bf16 Ps[128 * 72];
    const int t = threadIdx.x, w = t >> 6, lane = t & 63;
    const int l15 = lane & 15, quad = lane >> 4;
    const int qt = blockIdx.x, bh = blockIdx.y;
    const int b = bh >> 5, h = bh & 31, kvh = h >> 2;
    const int q0 = qt * 128;

    bf16x8 qf[2][4];
#pragma unroll
    for (int mi = 0; mi < 2; ++mi) {
        int qrow = b * SS + q0 + w * 32 + mi * 16 + l15;
#pragma unroll
        for (int ks = 0; ks < 4; ++ks)
            qf[mi][ks] = *(const bf16x8*)(Q + (size_t)qrow * DIM + h * HD + ks * 32 + quad * 8);
    }

    f32x4 of[2][8] = {};
    float mrow[2][4], lrow[2][4];
#pragma unroll
    for (int mi = 0; mi < 2; ++mi)
#pragma unroll
        for (int r = 0; r < 4; ++r) { mrow[mi][r] = NEGINF; lrow[mi][r] = 0.f; }

    const int kend = q0 + 128;
    for (int kk = 0; kk < kend; kk += 64) {
#pragma unroll
        for (int i = 0; i < 4; ++i) {
            int s = i * 256 + t;
            int key = s >> 4, slot = s & 15;
            int dseg = slot ^ (key & 15);
            async16((char*)Ks + (size_t)s * 16,
                    Kr + (size_t)(b * SS + kk + key) * KVDIM + kvh * HD + dseg * 8);
        }
#pragma unroll
        for (int i = 0; i < 4; ++i) {
            int s = i * 256 + t;
            int d = s >> 3, slot = s & 7;
            int kseg = slot ^ (d & 7);
            async16((char*)Vts + (size_t)s * 16,
                    Vt + ((size_t)((b * NKV + kvh) * HD + d)) * SS + kk + kseg * 8);
        }
        __syncthreads();

        f32x4 sacc[2][4] = {};
#pragma unroll
        for (int nt = 0; nt < 4; ++nt) {
            int key = nt * 16 + l15;
#pragma unroll
            for (int ks = 0; ks < 4; ++ks) {
                int slot = (ks * 4 + quad) ^ (key & 15);
                bf16x8 kf = *(const bf16x8*)(Ks + key * 128 + slot * 8);
#pragma unroll
                for (int mi = 0; mi < 2; ++mi)
                    sacc[mi][nt] = mfma16(qf[mi][ks], kf, sacc[mi][nt]);
            }
        }
        if (kk >= q0) {
#pragma unroll
            for (int mi = 0; mi < 2; ++mi)
#pragma unroll
                for (int nt = 0; nt < 4; ++nt) {
                    int key = kk + nt * 16 + l15;
#pragma unroll
                    for (int r = 0; r < 4; ++r) {
                        int q = q0 + w * 32 + mi * 16 + quad * 4 + r;
                        if (key > q) sacc[mi][nt][r] = NEGINF;
                    }
                }
        }
#pragma unroll
        for (int mi = 0; mi < 2; ++mi) {
#pragma unroll
            for (int r = 0; r < 4; ++r) {
                float mx = fmaxf(fmaxf(sacc[mi][0][r], sacc[mi][1][r]),
                                 fmaxf(sacc[mi][2][r], sacc[mi][3][r]));
#pragma unroll
                for (int off = 8; off >= 1; off >>= 1)
                    mx = fmaxf(mx, __shfl_xor(mx, off, 64));
                float mnew = fmaxf(mrow[mi][r], mx);
                float alpha = exp2f(mrow[mi][r] - mnew);
                float rsum = 0.f;
#pragma unroll
                for (int nt = 0; nt < 4; ++nt) {
                    float p = exp2f(sacc[mi][nt][r] - mnew);
                    sacc[mi][nt][r] = p;
                    rsum += p;
                }
#pragma unroll
                for (int off = 8; off >= 1; off >>= 1)
                    rsum += __shfl_xor(rsum, off, 64);
                lrow[mi][r] = lrow[mi][r] * alpha + rsum;
                mrow[mi][r] = mnew;
#pragma unroll
                for (int nt2 = 0; nt2 < 8; ++nt2) of[mi][nt2][r] *= alpha;
            }
        }
#pragma unroll
        for (int mi = 0; mi < 2; ++mi)
#pragma unroll
            for (int nt = 0; nt < 4; ++nt)
#pragma unroll
                for (int r = 0; r < 4; ++r)
                    Ps[(w * 32 + mi * 16 + quad * 4 + r) * 72 + nt * 16 + l15] =
                        (bf16)sacc[mi][nt][r];
        __syncthreads();
#pragma unroll
        for (int ks2 = 0; ks2 < 2; ++ks2) {
            bf16x8 pa[2];
#pragma unroll
            for (int mi = 0; mi < 2; ++mi)
                pa[mi] = *(const bf16x8*)(Ps + (w * 32 + mi * 16 + l15) * 72 + ks2 * 32 + quad * 8);
#pragma unroll
            for (int nt2 = 0; nt2 < 8; ++nt2) {
                int d = nt2 * 16 + l15;
                int slot = (ks2 * 4 + quad) ^ (d & 7);
                bf16x8 vb = *(const bf16x8*)(Vts + d * 64 + slot * 8);
#pragma unroll
                for (int mi = 0; mi < 2; ++mi)
                    of[mi][nt2] = mfma16(pa[mi], vb, of[mi][nt2]);
            }
        }
        __syncthreads();
    }
#pragma unroll
    for (int mi = 0; mi < 2; ++mi)
#pragma unroll
        for (int r = 0; r < 4; ++r) {
            float inv = 1.0f / lrow[mi][r];
            int qrow = b * SS + q0 + w * 32 + mi * 16 + quad * 4 + r;
#pragma unroll
            for (int nt2 = 0; nt2 < 8; ++nt2)
                AO[(size_t)qrow * DIM + h * HD + nt2 * 16 + l15] =
                    (bf16)(of[mi][nt2][r] * inv);
        }
}

// ---------------------------------------------------------------------------
extern "C" void kernel_launch(void* const* d_in, const int* in_sizes, int n_in,
                              void* d_out, int out_size, void* d_ws, size_t ws_size,
                              hipStream_t stream) {
    const size_t MD = (size_t)BB * SS * DIM;    // 16,777,216
    const size_t KV = (size_t)BB * SS * KVDIM;  //  4,194,304
    const size_t FC = (size_t)SS * (HD / 2);    //     131,072
    const int M = BB * SS;

    int* flags = (int*)d_ws;                    // 7 ints
    bf16* base = (bf16*)((char*)d_ws + 32);
    bf16* xb  = base;          // also reused as attention-output AO
    bf16* wb  = xb + MD;       // serially reused for wq/wk/wv/wo
    bf16* Q   = wb + MD;
    bf16* Kr  = Q + MD;
    bf16* Vw  = Kr + KV;
    bf16* Vt  = Vw + KV;
    bf16* fcb = Vt + KV;
    bf16* fsb = fcb + FC;

    DetectArgs da;
    for (int i = 0; i < 7; ++i) { da.p[i] = d_in[i]; da.n[i] = in_sizes[i]; }
    detect_dtypes<<<7, 256, 0, stream>>>(da, flags);

    dim3 blk(256);
    // x, freqs
    convert_to_bf16<<<(int)(MD / 8 / 256), blk, 0, stream>>>(d_in[0], xb, (int)(MD / 8), flags + 0);
    convert_to_bf16<<<(int)(FC / 8 / 256), blk, 0, stream>>>(d_in[5], fcb, (int)(FC / 8), flags + 5);
    convert_to_bf16<<<(int)(FC / 8 / 256), blk, 0, stream>>>(d_in[6], fsb, (int)(FC / 8), flags + 6);

    // Q projection
    convert_to_bf16<<<(int)(MD / 8 / 256), blk, 0, stream>>>(d_in[1], wb, (int)(MD / 8), flags + 1);
    gemm_nt<<<dim3(DIM / 128, M / 128), blk, 0, stream>>>(xb, wb, Q, M, DIM, DIM);
    // K projection
    convert_to_bf16<<<(int)(KV / 8 / 256), blk, 0, stream>>>(d_in[2], wb, (int)(KV / 8), flags + 2);
    gemm_nt<<<dim3(KVDIM / 128, M / 128), blk, 0, stream>>>(xb, wb, Kr, M, KVDIM, DIM);
    // V projection
    convert_to_bf16<<<(int)(KV / 8 / 256), blk, 0, stream>>>(d_in[3], wb, (int)(KV / 8), flags + 3);
    gemm_nt<<<dim3(KVDIM / 128, M / 128), blk, 0, stream>>>(xb, wb, Vw, M, KVDIM, DIM);

    // RoPE (Q pre-scaled by 1/sqrt(128)*log2e), V transpose
    rope_kernel<<<dim3((int)((MD / 8 + KV / 8) / 256)), blk, 0, stream>>>(Q, Kr, fcb, fsb);
    transpose_v<<<dim3(SS / 64, 16, BB), blk, 0, stream>>>(Vw, Vt);

    // Flash attention -> AO (reuses xb; x no longer needed)
    flash_attn<<<dim3(SS / 128, BB * NH), blk, 0, stream>>>(Q, Kr, Vt, xb);

    // Output projection (runtime-selected output dtype, keyed off x's dtype)
    convert_to_bf16<<<(int)(MD / 8 / 256), blk, 0, stream>>>(d_in[4], wb, (int)(MD / 8), flags + 4);
    gemm_nt_out<<<dim3(DIM / 128, M / 128), blk, 0, stream>>>(xb, wb, d_out, M, DIM, DIM, flags + 0);
}

// Round 3
// 961.664 us; speedup vs baseline: 1.2593x; 1.2593x over previous
//
#include <hip/hip_runtime.h>

typedef __bf16 bf16;
typedef __bf16 bf16x4 __attribute__((ext_vector_type(4)));
typedef __bf16 bf16x8 __attribute__((ext_vector_type(8)));
typedef float f32x4 __attribute__((ext_vector_type(4)));

#define BB 2
#define SS 2048
#define DIM 4096
#define KVDIM 1024
#define NH 32
#define NKV 8
#define HD 128
#define NEGINF (-1e30f)

__device__ __forceinline__ void async16(void* lds, const void* gmem) {
    __builtin_amdgcn_global_load_lds(
        (const __attribute__((address_space(1))) void*)gmem,
        (__attribute__((address_space(3))) void*)lds, 16, 0, 0);
}

__device__ __forceinline__ f32x4 mfma16(bf16x8 a, bf16x8 b, f32x4 c) {
    return __builtin_amdgcn_mfma_f32_16x16x32_bf16(a, b, c, 0, 0, 0);
}

// ---------------------------------------------------------------------------
// dtype detection (fp32 storage read as bf16 -> garbage magnitudes)
// ---------------------------------------------------------------------------
struct DetectArgs { const void* p[7]; int n[7]; };

__global__ void detect_dtypes(DetectArgs a, int* flags) {
    __shared__ int bad;
    const int ti = blockIdx.x;
    if (threadIdx.x == 0) bad = 0;
    __syncthreads();
    const bf16* s = (const bf16*)a.p[ti];
    int n = a.n[ti];
    int take = n < 8192 ? n : 8192;
    int lbad = 0;
    for (int i = threadIdx.x; i < take; i += 256) {
        float f = (float)s[i];
        if (!(f > -1e4f && f < 1e4f)) lbad = 1;
    }
    if (lbad) atomicOr(&bad, 1);
    __syncthreads();
    if (threadIdx.x == 0) flags[ti] = bad;
}

__global__ void convert_to_bf16(const void* __restrict__ src, bf16* __restrict__ dst,
                                int n8, const int* __restrict__ flagp) {
    int i = blockIdx.x * 256 + threadIdx.x;
    if (i >= n8) return;
    if (*flagp) {
        const float* s = (const float*)src + (size_t)i * 8;
        bf16x8 v;
#pragma unroll
        for (int j = 0; j < 8; ++j) v[j] = (bf16)s[j];
        *(bf16x8*)(dst + (size_t)i * 8) = v;
    } else {
        *(bf16x8*)(dst + (size_t)i * 8) = *((const bf16x8*)src + i);
    }
}

// ---------------------------------------------------------------------------
// NT GEMM (m97 structure)
// ---------------------------------------------------------------------------
__global__ __launch_bounds__(256, 2)
void gemm_nt(const bf16* __restrict__ A, const bf16* __restrict__ B,
             bf16* __restrict__ C, int M, int N, int K) {
    __shared__ bf16 As[128 * 32];
    __shared__ bf16 Bs[128 * 32];
    const int t = threadIdx.x;
    const int lane = t & 63;
    const int w = t >> 6;
    const int l15 = lane & 15, quad = lane >> 4;
    const int m0 = blockIdx.y * 128, n0 = blockIdx.x * 128;
    const int wm = (w >> 1) * 64, wn = (w & 1) * 64;

    f32x4 acc[4][4] = {};

    for (int k0 = 0; k0 < K; k0 += 32) {
#pragma unroll
        for (int i = 0; i < 2; ++i) {
            int s = i * 256 + t;
            int row = s >> 2, ks = s & 3;
            async16((char*)As + (size_t)s * 16, A + (size_t)(m0 + row) * K + k0 + ks * 8);
            async16((char*)Bs + (size_t)s * 16, B + (size_t)(n0 + row) * K + k0 + ks * 8);
        }
        __syncthreads();
        bf16x8 af[4], bfr[4];
#pragma unroll
        for (int i = 0; i < 4; ++i)
            af[i] = *(const bf16x8*)(As + (wm + i * 16 + l15) * 32 + quad * 8);
#pragma unroll
        for (int j = 0; j < 4; ++j)
            bfr[j] = *(const bf16x8*)(Bs + (wn + j * 16 + l15) * 32 + quad * 8);
#pragma unroll
        for (int i = 0; i < 4; ++i)
#pragma unroll
            for (int j = 0; j < 4; ++j)
                acc[i][j] = mfma16(af[i], bfr[j], acc[i][j]);
        __syncthreads();
    }
#pragma unroll
    for (int i = 0; i < 4; ++i)
#pragma unroll
        for (int j = 0; j < 4; ++j) {
            int col = n0 + wn + j * 16 + l15;
#pragma unroll
            for (int r = 0; r < 4; ++r)
                C[(size_t)(m0 + wm + i * 16 + quad * 4 + r) * N + col] = (bf16)acc[i][j][r];
        }
}

// Fused K+V projection: B = concat(wk, wv) [2048][4096]; C split into Kr / Vw.
__global__ __launch_bounds__(256, 2)
void gemm_nt_kv(const bf16* __restrict__ A, const bf16* __restrict__ Bkv,
                bf16* __restrict__ Kc, bf16* __restrict__ Vc, int M, int K) {
    __shared__ bf16 As[128 * 32];
    __shared__ bf16 Bs[128 * 32];
    const int t = threadIdx.x;
    const int lane = t & 63;
    const int w = t >> 6;
    const int l15 = lane & 15, quad = lane >> 4;
    const int m0 = blockIdx.y * 128, n0 = blockIdx.x * 128;
    const int wm = (w >> 1) * 64, wn = (w & 1) * 64;

    f32x4 acc[4][4] = {};

    for (int k0 = 0; k0 < K; k0 += 32) {
#pragma unroll
        for (int i = 0; i < 2; ++i) {
            int s = i * 256 + t;
            int row = s >> 2, ks = s & 3;
            async16((char*)As + (size_t)s * 16, A + (size_t)(m0 + row) * K + k0 + ks * 8);
            async16((char*)Bs + (size_t)s * 16, Bkv + (size_t)(n0 + row) * K + k0 + ks * 8);
        }
        __syncthreads();
        bf16x8 af[4], bfr[4];
#pragma unroll
        for (int i = 0; i < 4; ++i)
            af[i] = *(const bf16x8*)(As + (wm + i * 16 + l15) * 32 + quad * 8);
#pragma unroll
        for (int j = 0; j < 4; ++j)
            bfr[j] = *(const bf16x8*)(Bs + (wn + j * 16 + l15) * 32 + quad * 8);
#pragma unroll
        for (int i = 0; i < 4; ++i)
#pragma unroll
            for (int j = 0; j < 4; ++j)
                acc[i][j] = mfma16(af[i], bfr[j], acc[i][j]);
        __syncthreads();
    }
    bf16* C = (n0 < KVDIM) ? Kc : Vc;
    const int cb = (n0 < KVDIM) ? n0 : n0 - KVDIM;
#pragma unroll
    for (int i = 0; i < 4; ++i)
#pragma unroll
        for (int j = 0; j < 4; ++j) {
            int col = cb + wn + j * 16 + l15;
#pragma unroll
            for (int r = 0; r < 4; ++r)
                C[(size_t)(m0 + wm + i * 16 + quad * 4 + r) * KVDIM + col] = (bf16)acc[i][j][r];
        }
}

// O-proj with runtime output dtype
__global__ __launch_bounds__(256, 2)
void gemm_nt_out(const bf16* __restrict__ A, const bf16* __restrict__ B,
                 void* __restrict__ C, int M, int N, int K,
                 const int* __restrict__ flagp) {
    __shared__ bf16 As[128 * 32];
    __shared__ bf16 Bs[128 * 32];
    const int t = threadIdx.x;
    const int lane = t & 63;
    const int w = t >> 6;
    const int l15 = lane & 15, quad = lane >> 4;
    const int m0 = blockIdx.y * 128, n0 = blockIdx.x * 128;
    const int wm = (w >> 1) * 64, wn = (w & 1) * 64;
    const int f32out = *flagp;

    f32x4 acc[4][4] = {};

    for (int k0 = 0; k0 < K; k0 += 32) {
#pragma unroll
        for (int i = 0; i < 2; ++i) {
            int s = i * 256 + t;
            int row = s >> 2, ks = s & 3;
            async16((char*)As + (size_t)s * 16, A + (size_t)(m0 + row) * K + k0 + ks * 8);
            async16((char*)Bs + (size_t)s * 16, B + (size_t)(n0 + row) * K + k0 + ks * 8);
        }
        __syncthreads();
        bf16x8 af[4], bfr[4];
#pragma unroll
        for (int i = 0; i < 4; ++i)
            af[i] = *(const bf16x8*)(As + (wm + i * 16 + l15) * 32 + quad * 8);
#pragma unroll
        for (int j = 0; j < 4; ++j)
            bfr[j] = *(const bf16x8*)(Bs + (wn + j * 16 + l15) * 32 + quad * 8);
#pragma unroll
        for (int i = 0; i < 4; ++i)
#pragma unroll
            for (int j = 0; j < 4; ++j)
                acc[i][j] = mfma16(af[i], bfr[j], acc[i][j]);
        __syncthreads();
    }
#pragma unroll
    for (int i = 0; i < 4; ++i)
#pragma unroll
        for (int j = 0; j < 4; ++j) {
            int col = n0 + wn + j * 16 + l15;
#pragma unroll
            for (int r = 0; r < 4; ++r) {
                int row = m0 + wm + i * 16 + quad * 4 + r;
                if (f32out) ((float*)C)[(size_t)row * N + col] = acc[i][j][r];
                else        ((bf16*)C)[(size_t)row * N + col] = (bf16)acc[i][j][r];
            }
        }
}

// ---------------------------------------------------------------------------
// RoPE in place (Q pre-scaled by 1/sqrt(HD)*log2e)
// ---------------------------------------------------------------------------
__device__ __forceinline__ void rope8(bf16* p, const bf16* fc, const bf16* fs,
                                      int s, int i0, float sc) {
    bf16x8 v = *(bf16x8*)p;
    bf16x8 o;
#pragma unroll
    for (int j = 0; j < 4; ++j) {
        float tr = (float)v[2 * j], ti = (float)v[2 * j + 1];
        float cc = (float)fc[s * 64 + i0 + j];
        float sn = (float)fs[s * 64 + i0 + j];
        o[2 * j]     = (bf16)((tr * cc - ti * sn) * sc);
        o[2 * j + 1] = (bf16)((tr * sn + ti * cc) * sc);
    }
    *(bf16x8*)p = o;
}

__global__ void rope_kernel(bf16* __restrict__ Q, bf16* __restrict__ Kr,
                            const bf16* __restrict__ fc, const bf16* __restrict__ fs) {
    const float qscale = 0.08838834764831845f * 1.4426950408889634f;
    int u = blockIdx.x * 256 + threadIdx.x;
    const int QU = (DIM * (BB * SS)) / 8;
    if (u < QU) {
        int row = u >> 9;
        int c = (u & 511) * 8;
        rope8(Q + (size_t)row * DIM + c, fc, fs, row & (SS - 1), (c >> 1) & 63, qscale);
    } else {
        u -= QU;
        int row = u >> 7;
        int c = (u & 127) * 8;
        rope8(Kr + (size_t)row * KVDIM + c, fc, fs, row & (SS - 1), (c >> 1) & 63, 1.0f);
    }
}

// ---------------------------------------------------------------------------
// Transpose V -> Vt[((b*NKV+kvh)*HD + d)*S + s]
// ---------------------------------------------------------------------------
__global__ void transpose_v(const bf16* __restrict__ V, bf16* __restrict__ Vt) {
    __shared__ bf16 tile[64][74];
    const int st = blockIdx.x, ct = blockIdx.y, b = blockIdx.z;
    const int s0 = st * 64;
    const int kvh = ct >> 1, d0 = (ct & 1) * 64;
    const int t = threadIdx.x;
#pragma unroll
    for (int i = 0; i < 2; ++i) {
        int o = i * 256 + t;
        int r = o >> 3, c8 = (o & 7) * 8;
        bf16x8 v = *(const bf16x8*)(V + (size_t)(b * SS + s0 + r) * KVDIM + kvh * HD + d0 + c8);
#pragma unroll
        for (int j = 0; j < 8; ++j) tile[r][c8 + j] = v[j];
    }
    __syncthreads();
#pragma unroll
    for (int i = 0; i < 2; ++i) {
        int o = i * 256 + t;
        int sseg = (o & 7) * 8, dl = o >> 3;
        bf16x8 v;
#pragma unroll
        for (int j = 0; j < 8; ++j) v[j] = tile[sseg + j][dl];
        *(bf16x8*)(Vt + ((size_t)((b * NKV + kvh) * HD) + d0 + dl) * SS + s0 + sseg) = v;
    }
}

// ---------------------------------------------------------------------------
// Flash attention, S^T formulation: S^T = K*Q^T so each lane's score regs all
// belong to one q (col = lane&15) -> softmax needs only 2 shfls; P written to
// LDS as b64 vectors; PV computes O^T = V^T * P^T; epilogue transposes O^T
// through reused LDS for coalesced global stores. 2 barriers per k-tile.
// ---------------------------------------------------------------------------
__global__ __launch_bounds__(256, 2)
void flash_attn(const bf16* __restrict__ Q, const bf16* __restrict__ Kr,
                const bf16* __restrict__ Vt, bf16* __restrict__ AO) {
    __shared__ char smem[51200];
    bf16* Ks  = (bf16*)smem;               // [64 keys][128 d], 16B-slot swizzled
    bf16* Vts = (bf16*)(smem + 16384);     // [128 d][64 keys], swizzled
    bf16* Ps2 = (bf16*)(smem + 32768);     // [128 q][72] (64 keys + pad)
    const int t = threadIdx.x, w = t >> 6, lane = t & 63;
    const int l15 = lane & 15, quad = lane >> 4;
    const int bh = blockIdx.x;
    const int b = bh >> 5, h = bh & 31, kvh = h >> 2;
    const int q0 = ((int)gridDim.y - 1 - (int)blockIdx.y) * 128;  // LPT: longest first

    // Q fragments as B-operand: n = q = lane&15, k = quad*8+j
    bf16x8 qf[2][4];
#pragma unroll
    for (int mi = 0; mi < 2; ++mi) {
        int qrow = b * SS + q0 + w * 32 + mi * 16 + l15;
#pragma unroll
        for (int ks = 0; ks < 4; ++ks)
            qf[mi][ks] = *(const bf16x8*)(Q + (size_t)qrow * DIM + h * HD + ks * 32 + quad * 8);
    }

    f32x4 of[2][8] = {};                 // O^T: [q-tile mi][d-tile], col=q=l15
    float mrow[2] = {NEGINF, NEGINF};    // per-lane: stats for q = w*32+mi*16+l15
    float lrow[2] = {0.f, 0.f};

    const int kend = q0 + 128;
    for (int kk = 0; kk < kend; kk += 64) {
#pragma unroll
        for (int i = 0; i < 4; ++i) {
            int s = i * 256 + t;
            int key = s >> 4, slot = s & 15;
            int dseg = slot ^ (key & 15);
            async16((char*)Ks + (size_t)s * 16,
                    Kr + (size_t)(b * SS + kk + key) * KVDIM + kvh * HD + dseg * 8);
        }
#pragma unroll
        for (int i = 0; i < 4; ++i) {
            int s = i * 256 + t;
            int d = s >> 3, slot = s & 7;
            int kseg = slot ^ (d & 7);
            async16((char*)Vts + (size_t)s * 16,
                    Vt + ((size_t)((b * NKV + kvh) * HD + d)) * SS + kk + kseg * 8);
        }
        __syncthreads();

        // S^T = K * Q^T : rows = keys (A from Ks), cols = q (B from regs)
        f32x4 sacc[2][4] = {};
#pragma unroll
        for (int nt = 0; nt < 4; ++nt) {
            int key = nt * 16 + l15;
#pragma unroll
            for (int ks = 0; ks < 4; ++ks) {
                int slot = (ks * 4 + quad) ^ (key & 15);
                bf16x8 kf = *(const bf16x8*)(Ks + key * 128 + slot * 8);
#pragma unroll
                for (int mi = 0; mi < 2; ++mi)
                    sacc[mi][nt] = mfma16(kf, qf[mi][ks], sacc[mi][nt]);
            }
        }
        // causal mask: lane's q = q0+w*32+mi*16+l15; reg key = kk+nt*16+quad*4+r
        if (kk >= q0) {
#pragma unroll
            for (int mi = 0; mi < 2; ++mi) {
                int q = q0 + w * 32 + mi * 16 + l15;
#pragma unroll
                for (int nt = 0; nt < 4; ++nt) {
                    int kbase = kk + nt * 16 + quad * 4;
#pragma unroll
                    for (int r = 0; r < 4; ++r)
                        if (kbase + r > q) sacc[mi][nt][r] = NEGINF;
                }
            }
        }
        // online softmax: all 16 reg values are lane's own q; reduce regs then quads
#pragma unroll
        for (int mi = 0; mi < 2; ++mi) {
            float mx = sacc[mi][0][0];
#pragma unroll
            for (int nt = 0; nt < 4; ++nt)
#pragma unroll
                for (int r = 0; r < 4; ++r) mx = fmaxf(mx, sacc[mi][nt][r]);
            mx = fmaxf(mx, __shfl_xor(mx, 16));
            mx = fmaxf(mx, __shfl_xor(mx, 32));
            float mnew = fmaxf(mrow[mi], mx);
            float alpha = exp2f(mrow[mi] - mnew);
            float rsum = 0.f;
#pragma unroll
            for (int nt = 0; nt < 4; ++nt)
#pragma unroll
                for (int r = 0; r < 4; ++r) {
                    float p = exp2f(sacc[mi][nt][r] - mnew);
                    sacc[mi][nt][r] = p;
                    rsum += p;
                }
            rsum += __shfl_xor(rsum, 16);
            rsum += __shfl_xor(rsum, 32);
            lrow[mi] = lrow[mi] * alpha + rsum;
            mrow[mi] = mnew;
#pragma unroll
            for (int dt = 0; dt < 8; ++dt)
#pragma unroll
                for (int r = 0; r < 4; ++r) of[mi][dt][r] *= alpha;
        }
        // P^T regs -> Ps2[q][key] as b64 (4 contiguous keys per reg group).
        // Rows are wave-private: no barrier needed.
#pragma unroll
        for (int mi = 0; mi < 2; ++mi) {
            int row = w * 32 + mi * 16 + l15;
#pragma unroll
            for (int nt = 0; nt < 4; ++nt) {
                bf16x4 pv;
#pragma unroll
                for (int r = 0; r < 4; ++r) pv[r] = (bf16)sacc[mi][nt][r];
                *(bf16x4*)(Ps2 + row * 72 + nt * 16 + quad * 4) = pv;
            }
        }
        // O^T += V^T * P^T  (A = Vts fragments, B = own Ps2 rows)
#pragma unroll
        for (int kb = 0; kb < 2; ++kb) {
            bf16x8 pa[2];
#pragma unroll
            for (int mi = 0; mi < 2; ++mi)
                pa[mi] = *(const bf16x8*)(Ps2 + (w * 32 + mi * 16 + l15) * 72 + kb * 32 + quad * 8);
#pragma unroll
            for (int dt = 0; dt < 8; ++dt) {
                int d = dt * 16 + l15;
                int slot = (kb * 4 + quad) ^ (d & 7);
                bf16x8 vb = *(const bf16x8*)(Vts + d * 64 + slot * 8);
#pragma unroll
                for (int mi = 0; mi < 2; ++mi)
                    of[mi][dt] = mfma16(vb, pa[mi], of[mi][dt]);
            }
        }
        __syncthreads();  // protect Ks/Vts for next stage
    }
    // epilogue: O^T (col=q=l15, row=d=quad*4+r) -> transpose via LDS (reuse
    // Ks+Vts region as Os[128 q][128 d], 16B-slot swizzled), coalesced store.
    bf16* Os = (bf16*)smem;
#pragma unroll
    for (int mi = 0; mi < 2; ++mi) {
        float inv = 1.0f / lrow[mi];
        int row = w * 32 + mi * 16 + l15;
#pragma unroll
        for (int dt = 0; dt < 8; ++dt) {
            bf16x4 o4;
#pragma unroll
            for (int r = 0; r < 4; ++r) o4[r] = (bf16)(of[mi][dt][r] * inv);
            int s = dt * 2 + (quad >> 1);
            int slot = s ^ l15;
            *(bf16x4*)((char*)Os + row * 256 + slot * 16 + (quad & 1) * 8) = o4;
        }
    }
    __syncthreads();
#pragma unroll
    for (int i = 0; i < 8; ++i) {
        int flat = i * 256 + t;
        int ql = flat >> 4, s = flat & 15;
        bf16x8 v = *(const bf16x8*)((char*)Os + ql * 256 + (s ^ (ql & 15)) * 16);
        *(bf16x8*)(AO + (size_t)(b * SS + q0 + ql) * DIM + h * HD + s * 8) = v;
    }
}

// ---------------------------------------------------------------------------
extern "C" void kernel_launch(void* const* d_in, const int* in_sizes, int n_in,
                              void* d_out, int out_size, void* d_ws, size_t ws_size,
                              hipStream_t stream) {
    const size_t MD = (size_t)BB * SS * DIM;    // 16,777,216
    const size_t KV = (size_t)BB * SS * KVDIM;  //  4,194,304 (== wk/wv size)
    const size_t FC = (size_t)SS * (HD / 2);
    const int M = BB * SS;

    int* flags = (int*)d_ws;
    bf16* xb  = (bf16*)((char*)d_ws + 32);  // x, later reused as attn output AO
    bf16* wb  = xb + MD;                    // weight staging (wq | wk+wv | wo)
    bf16* Q   = wb + MD;
    bf16* Kr  = Q + MD;
    bf16* Vw  = Kr + KV;
    bf16* Vt  = Vw + KV;
    bf16* fcb = Vt + KV;
    bf16* fsb = fcb + FC;

    DetectArgs da;
    for (int i = 0; i < 7; ++i) { da.p[i] = d_in[i]; da.n[i] = in_sizes[i]; }
    detect_dtypes<<<7, 256, 0, stream>>>(da, flags);

    dim3 blk(256);
    convert_to_bf16<<<(int)(MD / 8 / 256), blk, 0, stream>>>(d_in[0], xb, (int)(MD / 8), flags + 0);
    convert_to_bf16<<<(int)(FC / 8 / 256), blk, 0, stream>>>(d_in[5], fcb, (int)(FC / 8), flags + 5);
    convert_to_bf16<<<(int)(FC / 8 / 256), blk, 0, stream>>>(d_in[6], fsb, (int)(FC / 8), flags + 6);

    // Q projection
    convert_to_bf16<<<(int)(MD / 8 / 256), blk, 0, stream>>>(d_in[1], wb, (int)(MD / 8), flags + 1);
    gemm_nt<<<dim3(DIM / 128, M / 128), blk, 0, stream>>>(xb, wb, Q, M, DIM, DIM);

    // fused K+V projection (wb = concat(wk, wv) rows)
    convert_to_bf16<<<(int)(KV / 8 / 256), blk, 0, stream>>>(d_in[2], wb, (int)(KV / 8), flags + 2);
    convert_to_bf16<<<(int)(KV / 8 / 256), blk, 0, stream>>>(d_in[3], wb + KV, (int)(KV / 8), flags + 3);
    gemm_nt_kv<<<dim3(2 * KVDIM / 128, M / 128), blk, 0, stream>>>(xb, wb, Kr, Vw, M, DIM);

    rope_kernel<<<dim3((int)((MD / 8 + KV / 8) / 256)), blk, 0, stream>>>(Q, Kr, fcb, fsb);
    transpose_v<<<dim3(SS / 64, 16, BB), blk, 0, stream>>>(Vw, Vt);

    // flash attention -> AO (reuses xb); grid: bh fastest, q-tiles LPT-ordered
    flash_attn<<<dim3(BB * NH, SS / 128), blk, 0, stream>>>(Q, Kr, Vt, xb);

    // output projection
    convert_to_bf16<<<(int)(MD / 8 / 256), blk, 0, stream>>>(d_in[4], wb, (int)(MD / 8), flags + 4);
    gemm_nt_out<<<dim3(DIM / 128, M / 128), blk, 0, stream>>>(xb, wb, d_out, M, DIM, DIM, flags + 0);
}

// Round 4
// 946.445 us; speedup vs baseline: 1.2796x; 1.0161x over previous
//
#include <hip/hip_runtime.h>

typedef __bf16 bf16;
typedef __bf16 bf16x4 __attribute__((ext_vector_type(4)));
typedef __bf16 bf16x8 __attribute__((ext_vector_type(8)));
typedef float f32x4 __attribute__((ext_vector_type(4)));

#define BB 2
#define SS 2048
#define DIM 4096
#define KVDIM 1024
#define NH 32
#define NKV 8
#define HD 128
#define NEGINF (-1e30f)

__device__ __forceinline__ void async16(void* lds, const void* gmem) {
    __builtin_amdgcn_global_load_lds(
        (const __attribute__((address_space(1))) void*)gmem,
        (__attribute__((address_space(3))) void*)lds, 16, 0, 0);
}

__device__ __forceinline__ f32x4 mfma16(bf16x8 a, bf16x8 b, f32x4 c) {
    return __builtin_amdgcn_mfma_f32_16x16x32_bf16(a, b, c, 0, 0, 0);
}

// ---------------------------------------------------------------------------
// dtype detection (fp32 storage read as bf16 -> garbage magnitudes)
// ---------------------------------------------------------------------------
struct DetectArgs { const void* p[7]; int n[7]; };

__global__ void detect_dtypes(DetectArgs a, int* flags) {
    __shared__ int bad;
    const int ti = blockIdx.x;
    if (threadIdx.x == 0) bad = 0;
    __syncthreads();
    const bf16* s = (const bf16*)a.p[ti];
    int n = a.n[ti];
    int take = n < 8192 ? n : 8192;
    int lbad = 0;
    for (int i = threadIdx.x; i < take; i += 256) {
        float f = (float)s[i];
        if (!(f > -1e4f && f < 1e4f)) lbad = 1;
    }
    if (lbad) atomicOr(&bad, 1);
    __syncthreads();
    if (threadIdx.x == 0) flags[ti] = bad;
}

__global__ void convert_to_bf16(const void* __restrict__ src, bf16* __restrict__ dst,
                                int n8, const int* __restrict__ flagp) {
    int i = blockIdx.x * 256 + threadIdx.x;
    if (i >= n8) return;
    if (*flagp) {
        const float* s = (const float*)src + (size_t)i * 8;
        bf16x8 v;
#pragma unroll
        for (int j = 0; j < 8; ++j) v[j] = (bf16)s[j];
        *(bf16x8*)(dst + (size_t)i * 8) = v;
    } else {
        *(bf16x8*)(dst + (size_t)i * 8) = *((const bf16x8*)src + i);
    }
}

// ---------------------------------------------------------------------------
// NT GEMM core, register-staged double buffer:
//   prefetch tile k+1 (global -> VGPR) is issued BEFORE compute of tile k;
//   ds_write of the prefetch happens at the top of the next iteration, after
//   the MFMAs -- its s_waitcnt vmcnt lands when loads are already complete,
//   taking global latency off the per-iteration critical path (vs the
//   global_load_lds + vmcnt(0)-before-barrier drain of the m97 structure).
// ---------------------------------------------------------------------------
__device__ __forceinline__ void gemm_core(const bf16* __restrict__ A,
                                          const bf16* __restrict__ B,
                                          int K, int m0, int n0,
                                          f32x4 (&acc)[4][4]) {
    __shared__ bf16 As[128 * 32];
    __shared__ bf16 Bs[128 * 32];
    const int t = threadIdx.x;
    const int lane = t & 63, w = t >> 6;
    const int l15 = lane & 15, quad = lane >> 4;
    const int wm = (w >> 1) * 64, wn = (w & 1) * 64;

    // staging coords: thread t owns 16B segments s=t and s=t+256 (of 512);
    // seg s -> row = s>>2, k-offset = (s&3)*8; LDS elem offset = s*8.
    const int r0 = t >> 2, ks8 = (t & 3) * 8;
    const bf16* a0p = A + (size_t)(m0 + r0) * K + ks8;
    const bf16* a1p = a0p + (size_t)64 * K;
    const bf16* b0p = B + (size_t)(n0 + r0) * K + ks8;
    const bf16* b1p = b0p + (size_t)64 * K;

    bf16x8 ra0 = *(const bf16x8*)a0p;
    bf16x8 ra1 = *(const bf16x8*)a1p;
    bf16x8 rb0 = *(const bf16x8*)b0p;
    bf16x8 rb1 = *(const bf16x8*)b1p;

    for (int k0 = 0; k0 < K; k0 += 32) {
        __syncthreads();                       // previous tile fully consumed
        *(bf16x8*)(As + t * 8)        = ra0;
        *(bf16x8*)(As + t * 8 + 2048) = ra1;
        *(bf16x8*)(Bs + t * 8)        = rb0;
        *(bf16x8*)(Bs + t * 8 + 2048) = rb1;
        __syncthreads();                       // tile visible

        int kn = k0 + 32;
        if (kn >= K) kn = 0;                   // dummy reload of tile 0 (valid mem)
        ra0 = *(const bf16x8*)(a0p + kn);
        ra1 = *(const bf16x8*)(a1p + kn);
        rb0 = *(const bf16x8*)(b0p + kn);
        rb1 = *(const bf16x8*)(b1p + kn);

        bf16x8 af[4], bfr[4];
#pragma unroll
        for (int i = 0; i < 4; ++i)
            af[i] = *(const bf16x8*)(As + (wm + i * 16 + l15) * 32 + quad * 8);
#pragma unroll
        for (int j = 0; j < 4; ++j)
            bfr[j] = *(const bf16x8*)(Bs + (wn + j * 16 + l15) * 32 + quad * 8);
#pragma unroll
        for (int i = 0; i < 4; ++i)
#pragma unroll
            for (int j = 0; j < 4; ++j)
                acc[i][j] = mfma16(af[i], bfr[j], acc[i][j]);
    }
}

__global__ __launch_bounds__(256, 2)
void gemm_nt(const bf16* __restrict__ A, const bf16* __restrict__ B,
             bf16* __restrict__ C, int M, int N, int K) {
    const int t = threadIdx.x, lane = t & 63, w = t >> 6;
    const int l15 = lane & 15, quad = lane >> 4;
    const int m0 = blockIdx.y * 128, n0 = blockIdx.x * 128;
    const int wm = (w >> 1) * 64, wn = (w & 1) * 64;
    f32x4 acc[4][4] = {};
    gemm_core(A, B, K, m0, n0, acc);
#pragma unroll
    for (int i = 0; i < 4; ++i)
#pragma unroll
        for (int j = 0; j < 4; ++j) {
            int col = n0 + wn + j * 16 + l15;
#pragma unroll
            for (int r = 0; r < 4; ++r)
                C[(size_t)(m0 + wm + i * 16 + quad * 4 + r) * N + col] = (bf16)acc[i][j][r];
        }
}

// Fused K+V projection: B = concat(wk, wv); C split into Kc / Vc.
__global__ __launch_bounds__(256, 2)
void gemm_nt_kv(const bf16* __restrict__ A, const bf16* __restrict__ Bkv,
                bf16* __restrict__ Kc, bf16* __restrict__ Vc, int M, int K) {
    const int t = threadIdx.x, lane = t & 63, w = t >> 6;
    const int l15 = lane & 15, quad = lane >> 4;
    const int m0 = blockIdx.y * 128, n0 = blockIdx.x * 128;
    const int wm = (w >> 1) * 64, wn = (w & 1) * 64;
    f32x4 acc[4][4] = {};
    gemm_core(A, Bkv, K, m0, n0, acc);
    bf16* C = (n0 < KVDIM) ? Kc : Vc;
    const int cb = (n0 < KVDIM) ? n0 : n0 - KVDIM;
#pragma unroll
    for (int i = 0; i < 4; ++i)
#pragma unroll
        for (int j = 0; j < 4; ++j) {
            int col = cb + wn + j * 16 + l15;
#pragma unroll
            for (int r = 0; r < 4; ++r)
                C[(size_t)(m0 + wm + i * 16 + quad * 4 + r) * KVDIM + col] = (bf16)acc[i][j][r];
        }
}

// O-proj with runtime output dtype
__global__ __launch_bounds__(256, 2)
void gemm_nt_out(const bf16* __restrict__ A, const bf16* __restrict__ B,
                 void* __restrict__ C, int M, int N, int K,
                 const int* __restrict__ flagp) {
    const int t = threadIdx.x, lane = t & 63, w = t >> 6;
    const int l15 = lane & 15, quad = lane >> 4;
    const int m0 = blockIdx.y * 128, n0 = blockIdx.x * 128;
    const int wm = (w >> 1) * 64, wn = (w & 1) * 64;
    const int f32out = *flagp;
    f32x4 acc[4][4] = {};
    gemm_core(A, B, K, m0, n0, acc);
#pragma unroll
    for (int i = 0; i < 4; ++i)
#pragma unroll
        for (int j = 0; j < 4; ++j) {
            int col = n0 + wn + j * 16 + l15;
#pragma unroll
            for (int r = 0; r < 4; ++r) {
                int row = m0 + wm + i * 16 + quad * 4 + r;
                if (f32out) ((float*)C)[(size_t)row * N + col] = acc[i][j][r];
                else        ((bf16*)C)[(size_t)row * N + col] = (bf16)acc[i][j][r];
            }
        }
}

// ---------------------------------------------------------------------------
// RoPE in place (Q pre-scaled by 1/sqrt(HD)*log2e)
// ---------------------------------------------------------------------------
__device__ __forceinline__ void rope8(bf16* p, const bf16* fc, const bf16* fs,
                                      int s, int i0, float sc) {
    bf16x8 v = *(bf16x8*)p;
    bf16x8 o;
#pragma unroll
    for (int j = 0; j < 4; ++j) {
        float tr = (float)v[2 * j], ti = (float)v[2 * j + 1];
        float cc = (float)fc[s * 64 + i0 + j];
        float sn = (float)fs[s * 64 + i0 + j];
        o[2 * j]     = (bf16)((tr * cc - ti * sn) * sc);
        o[2 * j + 1] = (bf16)((tr * sn + ti * cc) * sc);
    }
    *(bf16x8*)p = o;
}

__global__ void rope_kernel(bf16* __restrict__ Q, bf16* __restrict__ Kr,
                            const bf16* __restrict__ fc, const bf16* __restrict__ fs) {
    const float qscale = 0.08838834764831845f * 1.4426950408889634f;
    int u = blockIdx.x * 256 + threadIdx.x;
    const int QU = (DIM * (BB * SS)) / 8;
    if (u < QU) {
        int row = u >> 9;
        int c = (u & 511) * 8;
        rope8(Q + (size_t)row * DIM + c, fc, fs, row & (SS - 1), (c >> 1) & 63, qscale);
    } else {
        u -= QU;
        int row = u >> 7;
        int c = (u & 127) * 8;
        rope8(Kr + (size_t)row * KVDIM + c, fc, fs, row & (SS - 1), (c >> 1) & 63, 1.0f);
    }
}

// ---------------------------------------------------------------------------
// Transpose V -> Vt[((b*NKV+kvh)*HD + d)*S + s]
// ---------------------------------------------------------------------------
__global__ void transpose_v(const bf16* __restrict__ V, bf16* __restrict__ Vt) {
    __shared__ bf16 tile[64][74];
    const int st = blockIdx.x, ct = blockIdx.y, b = blockIdx.z;
    const int s0 = st * 64;
    const int kvh = ct >> 1, d0 = (ct & 1) * 64;
    const int t = threadIdx.x;
#pragma unroll
    for (int i = 0; i < 2; ++i) {
        int o = i * 256 + t;
        int r = o >> 3, c8 = (o & 7) * 8;
        bf16x8 v = *(const bf16x8*)(V + (size_t)(b * SS + s0 + r) * KVDIM + kvh * HD + d0 + c8);
#pragma unroll
        for (int j = 0; j < 8; ++j) tile[r][c8 + j] = v[j];
    }
    __syncthreads();
#pragma unroll
    for (int i = 0; i < 2; ++i) {
        int o = i * 256 + t;
        int sseg = (o & 7) * 8, dl = o >> 3;
        bf16x8 v;
#pragma unroll
        for (int j = 0; j < 8; ++j) v[j] = tile[sseg + j][dl];
        *(bf16x8*)(Vt + ((size_t)((b * NKV + kvh) * HD) + d0 + dl) * SS + s0 + sseg) = v;
    }
}

// ---------------------------------------------------------------------------
// Flash attention, S^T formulation (unchanged from R3 win)
// ---------------------------------------------------------------------------
__global__ __launch_bounds__(256, 2)
void flash_attn(const bf16* __restrict__ Q, const bf16* __restrict__ Kr,
                const bf16* __restrict__ Vt, bf16* __restrict__ AO) {
    __shared__ char smem[51200];
    bf16* Ks  = (bf16*)smem;               // [64 keys][128 d], 16B-slot swizzled
    bf16* Vts = (bf16*)(smem + 16384);     // [128 d][64 keys], swizzled
    bf16* Ps2 = (bf16*)(smem + 32768);     // [128 q][72]
    const int t = threadIdx.x, w = t >> 6, lane = t & 63;
    const int l15 = lane & 15, quad = lane >> 4;
    const int bh = blockIdx.x;
    const int b = bh >> 5, h = bh & 31, kvh = h >> 2;
    const int q0 = ((int)gridDim.y - 1 - (int)blockIdx.y) * 128;  // LPT

    bf16x8 qf[2][4];
#pragma unroll
    for (int mi = 0; mi < 2; ++mi) {
        int qrow = b * SS + q0 + w * 32 + mi * 16 + l15;
#pragma unroll
        for (int ks = 0; ks < 4; ++ks)
            qf[mi][ks] = *(const bf16x8*)(Q + (size_t)qrow * DIM + h * HD + ks * 32 + quad * 8);
    }

    f32x4 of[2][8] = {};
    float mrow[2] = {NEGINF, NEGINF};
    float lrow[2] = {0.f, 0.f};

    const int kend = q0 + 128;
    for (int kk = 0; kk < kend; kk += 64) {
#pragma unroll
        for (int i = 0; i < 4; ++i) {
            int s = i * 256 + t;
            int key = s >> 4, slot = s & 15;
            int dseg = slot ^ (key & 15);
            async16((char*)Ks + (size_t)s * 16,
                    Kr + (size_t)(b * SS + kk + key) * KVDIM + kvh * HD + dseg * 8);
        }
#pragma unroll
        for (int i = 0; i < 4; ++i) {
            int s = i * 256 + t;
            int d = s >> 3, slot = s & 7;
            int kseg = slot ^ (d & 7);
            async16((char*)Vts + (size_t)s * 16,
                    Vt + ((size_t)((b * NKV + kvh) * HD + d)) * SS + kk + kseg * 8);
        }
        __syncthreads();

        f32x4 sacc[2][4] = {};
#pragma unroll
        for (int nt = 0; nt < 4; ++nt) {
            int key = nt * 16 + l15;
#pragma unroll
            for (int ks = 0; ks < 4; ++ks) {
                int slot = (ks * 4 + quad) ^ (key & 15);
                bf16x8 kf = *(const bf16x8*)(Ks + key * 128 + slot * 8);
#pragma unroll
                for (int mi = 0; mi < 2; ++mi)
                    sacc[mi][nt] = mfma16(kf, qf[mi][ks], sacc[mi][nt]);
            }
        }
        if (kk >= q0) {
#pragma unroll
            for (int mi = 0; mi < 2; ++mi) {
                int q = q0 + w * 32 + mi * 16 + l15;
#pragma unroll
                for (int nt = 0; nt < 4; ++nt) {
                    int kbase = kk + nt * 16 + quad * 4;
#pragma unroll
                    for (int r = 0; r < 4; ++r)
                        if (kbase + r > q) sacc[mi][nt][r] = NEGINF;
                }
            }
        }
#pragma unroll
        for (int mi = 0; mi < 2; ++mi) {
            float mx = sacc[mi][0][0];
#pragma unroll
            for (int nt = 0; nt < 4; ++nt)
#pragma unroll
                for (int r = 0; r < 4; ++r) mx = fmaxf(mx, sacc[mi][nt][r]);
            mx = fmaxf(mx, __shfl_xor(mx, 16));
            mx = fmaxf(mx, __shfl_xor(mx, 32));
            float mnew = fmaxf(mrow[mi], mx);
            float alpha = exp2f(mrow[mi] - mnew);
            float rsum = 0.f;
#pragma unroll
            for (int nt = 0; nt < 4; ++nt)
#pragma unroll
                for (int r = 0; r < 4; ++r) {
                    float p = exp2f(sacc[mi][nt][r] - mnew);
                    sacc[mi][nt][r] = p;
                    rsum += p;
                }
            rsum += __shfl_xor(rsum, 16);
            rsum += __shfl_xor(rsum, 32);
            lrow[mi] = lrow[mi] * alpha + rsum;
            mrow[mi] = mnew;
#pragma unroll
            for (int dt = 0; dt < 8; ++dt)
#pragma unroll
                for (int r = 0; r < 4; ++r) of[mi][dt][r] *= alpha;
        }
#pragma unroll
        for (int mi = 0; mi < 2; ++mi) {
            int row = w * 32 + mi * 16 + l15;
#pragma unroll
            for (int nt = 0; nt < 4; ++nt) {
                bf16x4 pv;
#pragma unroll
                for (int r = 0; r < 4; ++r) pv[r] = (bf16)sacc[mi][nt][r];
                *(bf16x4*)(Ps2 + row * 72 + nt * 16 + quad * 4) = pv;
            }
        }
#pragma unroll
        for (int kb = 0; kb < 2; ++kb) {
            bf16x8 pa[2];
#pragma unroll
            for (int mi = 0; mi < 2; ++mi)
                pa[mi] = *(const bf16x8*)(Ps2 + (w * 32 + mi * 16 + l15) * 72 + kb * 32 + quad * 8);
#pragma unroll
            for (int dt = 0; dt < 8; ++dt) {
                int d = dt * 16 + l15;
                int slot = (kb * 4 + quad) ^ (d & 7);
                bf16x8 vb = *(const bf16x8*)(Vts + d * 64 + slot * 8);
#pragma unroll
                for (int mi = 0; mi < 2; ++mi)
                    of[mi][dt] = mfma16(vb, pa[mi], of[mi][dt]);
            }
        }
        __syncthreads();
    }
    bf16* Os = (bf16*)smem;
#pragma unroll
    for (int mi = 0; mi < 2; ++mi) {
        float inv = 1.0f / lrow[mi];
        int row = w * 32 + mi * 16 + l15;
#pragma unroll
        for (int dt = 0; dt < 8; ++dt) {
            bf16x4 o4;
#pragma unroll
            for (int r = 0; r < 4; ++r) o4[r] = (bf16)(of[mi][dt][r] * inv);
            int s = dt * 2 + (quad >> 1);
            int slot = s ^ l15;
            *(bf16x4*)((char*)Os + row * 256 + slot * 16 + (quad & 1) * 8) = o4;
        }
    }
    __syncthreads();
#pragma unroll
    for (int i = 0; i < 8; ++i) {
        int flat = i * 256 + t;
        int ql = flat >> 4, s = flat & 15;
        bf16x8 v = *(const bf16x8*)((char*)Os + ql * 256 + (s ^ (ql & 15)) * 16);
        *(bf16x8*)(AO + (size_t)(b * SS + q0 + ql) * DIM + h * HD + s * 8) = v;
    }
}

// ---------------------------------------------------------------------------
extern "C" void kernel_launch(void* const* d_in, const int* in_sizes, int n_in,
                              void* d_out, int out_size, void* d_ws, size_t ws_size,
                              hipStream_t stream) {
    const size_t MD = (size_t)BB * SS * DIM;    // 16,777,216
    const size_t KV = (size_t)BB * SS * KVDIM;  //  4,194,304
    const size_t FC = (size_t)SS * (HD / 2);
    const int M = BB * SS;

    int* flags = (int*)d_ws;
    bf16* xb  = (bf16*)((char*)d_ws + 32);  // x, later reused as attn output AO
    bf16* wb  = xb + MD;                    // weight staging (wq | wk+wv | wo)
    bf16* Q   = wb + MD;
    bf16* Kr  = Q + MD;
    bf16* Vw  = Kr + KV;
    bf16* Vt  = Vw + KV;
    bf16* fcb = Vt + KV;
    bf16* fsb = fcb + FC;

    DetectArgs da;
    for (int i = 0; i < 7; ++i) { da.p[i] = d_in[i]; da.n[i] = in_sizes[i]; }
    detect_dtypes<<<7, 256, 0, stream>>>(da, flags);

    dim3 blk(256);
    convert_to_bf16<<<(int)(MD / 8 / 256), blk, 0, stream>>>(d_in[0], xb, (int)(MD / 8), flags + 0);
    convert_to_bf16<<<(int)(FC / 8 / 256), blk, 0, stream>>>(d_in[5], fcb, (int)(FC / 8), flags + 5);
    convert_to_bf16<<<(int)(FC / 8 / 256), blk, 0, stream>>>(d_in[6], fsb, (int)(FC / 8), flags + 6);

    // Q projection
    convert_to_bf16<<<(int)(MD / 8 / 256), blk, 0, stream>>>(d_in[1], wb, (int)(MD / 8), flags + 1);
    gemm_nt<<<dim3(DIM / 128, M / 128), blk, 0, stream>>>(xb, wb, Q, M, DIM, DIM);

    // fused K+V projection
    convert_to_bf16<<<(int)(KV / 8 / 256), blk, 0, stream>>>(d_in[2], wb, (int)(KV / 8), flags + 2);
    convert_to_bf16<<<(int)(KV / 8 / 256), blk, 0, stream>>>(d_in[3], wb + KV, (int)(KV / 8), flags + 3);
    gemm_nt_kv<<<dim3(2 * KVDIM / 128, M / 128), blk, 0, stream>>>(xb, wb, Kr, Vw, M, DIM);

    rope_kernel<<<dim3((int)((MD / 8 + KV / 8) / 256)), blk, 0, stream>>>(Q, Kr, fcb, fsb);
    transpose_v<<<dim3(SS / 64, 16, BB), blk, 0, stream>>>(Vw, Vt);

    // flash attention -> AO (reuses xb)
    flash_attn<<<dim3(BB * NH, SS / 128), blk, 0, stream>>>(Q, Kr, Vt, xb);

    // output projection
    convert_to_bf16<<<(int)(MD / 8 / 256), blk, 0, stream>>>(d_in[4], wb, (int)(MD / 8), flags + 4);
    gemm_nt_out<<<dim3(DIM / 128, M / 128), blk, 0, stream>>>(xb, wb, d_out, M, DIM, DIM, flags + 0);
}